// Round 9
// baseline (274.712 us; speedup 1.0000x reference)
//
#include <hip/hip_runtime.h>
#include <math.h>

#define NF 39
#define CONT_F 13
#define CATE_F 26
#define EMB_D 40
#define VOCAB 100000
#define NCH 9              // 8 attn channels + 1 fc channel
#define ROW_B 40           // fp8 row: 40 B
#define CH_B (NF * ROW_B)  // 1560 B per channel
#define CH_W (NF * 10)     // 390 words per channel
#define REP 5              // grid redundancy for rocprof visibility

typedef __attribute__((ext_vector_type(4))) float f32x4;
typedef __attribute__((ext_vector_type(2))) float f32x2;

// ---- fp32 -> 2x OCP e4m3, HW packed-cvt (op_sel immediate via template) ----
__device__ __forceinline__ unsigned f32_to_e4m3_sw(float f) {
    unsigned u = __float_as_uint(f);
    unsigned s = (u >> 24) & 0x80u;
    int e = (int)((u >> 23) & 0xFFu) - 127;
    unsigned m = u & 0x7FFFFFu;
    if (e < -6) return s;
    unsigned m3 = (m + 0x7FFFFu + ((m >> 20) & 1u)) >> 20;
    if (m3 >= 8u) { m3 -= 8u; ++e; }
    if (e > 8) { e = 8; m3 = 6u; }
    return s | ((unsigned)(e + 7) << 3) | m3;
}

template <bool HI>
__device__ __forceinline__ unsigned cvt2_fp8(float a, float b, unsigned old) {
#if __has_builtin(__builtin_amdgcn_cvt_pk_fp8_f32)
    return __builtin_amdgcn_cvt_pk_fp8_f32(a, b, old, HI);
#else
    unsigned p = f32_to_e4m3_sw(a) | (f32_to_e4m3_sw(b) << 8);
    return HI ? ((old & 0x0000FFFFu) | (p << 16)) : ((old & 0xFFFF0000u) | p);
#endif
}

__device__ __forceinline__ int clamp_row(int r) { return r > NF - 1 ? NF - 1 : r; }

// launch_bounds(192,8): 8 waves/EU -> 32 waves/CU cap; blocks/CU then
// LDS-limited at 10 (15.6 KB each). VGPR target 64; we measured 40.
__global__ __launch_bounds__(192, 8)
void afm_fp8_kernel(const float* __restrict__ conts,   // (B,13)
                    const int*   __restrict__ cates,   // (B,26)
                    const float* __restrict__ emb,     // (100000,40)
                    const float* __restrict__ attn_W,  // (8,40)
                    const float* __restrict__ attn_b,  // (8,)
                    const float* __restrict__ proj_W,  // (1,8)
                    const float* __restrict__ fc_W,    // (1,40)
                    const float* __restrict__ fc_b,    // (1,)
                    float* __restrict__ out,           // (B,1)
                    int rowmask)
{
    __shared__ __attribute__((aligned(16))) unsigned char Xb[NF * ROW_B];
    __shared__ __attribute__((aligned(16))) unsigned char Aall[NCH * CH_B];
    __shared__ float reds[3], redg[3];

    const int tid = threadIdx.x;
    const int row = blockIdx.x & rowmask;   // REP blocks/row, identical writes

    // ---------------- phase 1: stage fp8 X + 9 scaled copies ----------------
    // f32x4 vector arithmetic -> v_pk_mul_f32 (2 slots per 4 elems).
    {
        const f32x4* emb4 = (const f32x4*)emb;
        const f32x4* aW4  = (const f32x4*)attn_W;
        const f32x4* fW4  = (const f32x4*)fc_W;
        unsigned* XbW = (unsigned*)Xb;
        unsigned* AW  = (unsigned*)Aall;
        const float SC = 0x1p20f;  // 2^20 operand pre-scale (e4m3 range)
        for (int t = tid; t < NF * 10; t += 192) {
            const int f = t / 10, q = t % 10;
            f32x4 v;
            if (f < CONT_F) {
                v = emb4[f * 10 + q] * (conts[row * CONT_F + f] * SC);
            } else {
                unsigned u = (unsigned)cates[row * CATE_F + (f - CONT_F)];
                if (u >= (unsigned)VOCAB) u = 0;
                v = emb4[u * 10 + q] * SC;
            }
            unsigned xw = cvt2_fp8<false>(v[0], v[1], 0u);
            xw = cvt2_fp8<true>(v[2], v[3], xw);
            XbW[f * 10 + q] = xw;
            #pragma unroll
            for (int c = 0; c < NCH; ++c) {
                const f32x4 wv = (c < 8) ? aW4[c * 10 + q] : fW4[q];
                const f32x4 av = v * wv;
                unsigned aw = cvt2_fp8<false>(av[0], av[1], 0u);
                aw = cvt2_fp8<true>(av[2], av[3], aw);
                AW[c * CH_W + f * 10 + q] = aw;
            }
        }
    }
    __syncthreads();

    // ---------------- phase 2: 9-channel fp8 Gram, 2 tiles/wave -------------
    const int wid  = tid >> 6;
    const int lane = tid & 63;
    const int l15  = lane & 15;
    const int quad = lane >> 4;

    const int TM[3][2] = {{0, 0}, {0, 1}, {1, 2}};
    const int TN[3][2] = {{0, 1}, {2, 1}, {2, 2}};
    const int mt0 = TM[wid][0], mt1 = TM[wid][1];
    const int nt0 = TN[wid][0], nt1 = TN[wid][1];

    const int rA0 = clamp_row(mt0 * 16 + l15);
    const int rA1 = clamp_row(mt1 * 16 + l15);
    const int rB0 = clamp_row(nt0 * 16 + l15);
    const int rB1 = clamp_row(nt1 * 16 + l15);

    const unsigned char* XbP = Xb;
    long b0[2], b1[2];
    b0[0] = *(const long*)(XbP + rB0 * ROW_B + quad * 8);
    b1[0] = (quad == 0) ? *(const long*)(XbP + rB0 * ROW_B + 32) : 0L;
    b0[1] = *(const long*)(XbP + rB1 * ROW_B + quad * 8);
    b1[1] = (quad == 0) ? *(const long*)(XbP + rB1 * ROW_B + 32) : 0L;

    // INV pre-folded: relu(z*INV+b)*pj == relu(z + b*2^40) * (pj*INV), exact.
    const float INV = 0x1p-40f;
    float pjI[8], bbS[8];
    #pragma unroll
    for (int a = 0; a < 8; ++a) {
        pjI[a] = proj_W[a] * INV;
        bbS[a] = attn_b[a] * 0x1p40f;
    }

    // packed-fp32 fold accumulators: [tile][r-half], 2 lanes = 2 r slots
    f32x2 lac[2][2] = {{{0.f, 0.f}, {0.f, 0.f}}, {{0.f, 0.f}, {0.f, 0.f}}};
    f32x4 gv[2];
    const f32x2 zz = {0.f, 0.f};

    #pragma unroll
    for (int c = 0; c < NCH; ++c) {
        const unsigned char* aB = Aall + c * CH_B;
        const long a00 = *(const long*)(aB + rA0 * ROW_B + quad * 8);
        const long a01 = (quad == 0) ? *(const long*)(aB + rA0 * ROW_B + 32) : 0L;
        const long a10 = *(const long*)(aB + rA1 * ROW_B + quad * 8);
        const long a11 = (quad == 0) ? *(const long*)(aB + rA1 * ROW_B + 32) : 0L;
        f32x4 z0 = {0.f, 0.f, 0.f, 0.f};
        f32x4 z1 = {0.f, 0.f, 0.f, 0.f};
        z0 = __builtin_amdgcn_mfma_f32_16x16x32_fp8_fp8(a00, b0[0], z0, 0, 0, 0);
        z0 = __builtin_amdgcn_mfma_f32_16x16x32_fp8_fp8(a01, b1[0], z0, 0, 0, 0);
        z1 = __builtin_amdgcn_mfma_f32_16x16x32_fp8_fp8(a10, b0[1], z1, 0, 0, 0);
        z1 = __builtin_amdgcn_mfma_f32_16x16x32_fp8_fp8(a11, b1[1], z1, 0, 0, 0);
        if (c < 8) {
            const f32x2 bb2 = {bbS[c], bbS[c]};
            const f32x2 pj2 = {pjI[c], pjI[c]};
            f32x2 t00 = {z0[0], z0[1]};
            f32x2 t01 = {z0[2], z0[3]};
            f32x2 t10 = {z1[0], z1[1]};
            f32x2 t11 = {z1[2], z1[3]};
            t00 = __builtin_elementwise_max(t00 + bb2, zz);   // pk_add + pk_max
            t01 = __builtin_elementwise_max(t01 + bb2, zz);
            t10 = __builtin_elementwise_max(t10 + bb2, zz);
            t11 = __builtin_elementwise_max(t11 + bb2, zz);
            lac[0][0] += pj2 * t00;                           // contracts to pk_fma
            lac[0][1] += pj2 * t01;
            lac[1][0] += pj2 * t10;
            lac[1][1] += pj2 * t11;
        } else {
            gv[0] = z0;
            gv[1] = z1;
        }
    }

    // ---------------- phase 3: max-free softmax + epilogue ------------------
    float s = 0.f, gs = 0.f;
    #pragma unroll
    for (int t = 0; t < 2; ++t) {
        const int mt = (t == 0) ? mt0 : mt1;
        const int nt = (t == 0) ? nt0 : nt1;
        #pragma unroll
        for (int r = 0; r < 4; ++r) {
            const int i = mt * 16 + quad * 4 + r;
            const int j = nt * 16 + l15;
            if (i < j && j < NF) {
                const float e = __expf(lac[t][r >> 1][r & 1]);
                s += e;
                gs = fmaf(e, gv[t][r], gs);   // g carries 2^40; undone once below
            }
        }
    }
    #pragma unroll
    for (int off = 32; off; off >>= 1) {
        s  += __shfl_xor(s, off);
        gs += __shfl_xor(gs, off);
    }
    if (lane == 0) { reds[wid] = s; redg[wid] = gs; }
    __syncthreads();

    if (tid == 0) {
        const float S = reds[0] + reds[1] + reds[2];
        const float G = (redg[0] + redg[1] + redg[2]) * INV;
        const float zf = G / S + fc_b[0];
        out[row] = 1.f / (1.f + __expf(-zf));
    }
}

extern "C" void kernel_launch(void* const* d_in, const int* in_sizes, int n_in,
                              void* d_out, int out_size, void* d_ws, size_t ws_size,
                              hipStream_t stream) {
    const float* conts  = (const float*)d_in[0];
    const int*   cates  = (const int*)  d_in[1];
    // d_in[2] = combs: unused by the reference computation
    const float* emb    = (const float*)d_in[3];
    const float* attn_W = (const float*)d_in[4];
    const float* attn_b = (const float*)d_in[5];
    const float* proj_W = (const float*)d_in[6];
    const float* fc_W   = (const float*)d_in[7];
    const float* fc_b   = (const float*)d_in[8];
    float* out = (float*)d_out;

    const int batch = in_sizes[0] / CONT_F;  // 4096 (power of 2)

    // MEASUREMENT: REP x grid redundancy keeps the kernel visible in rocprof
    // top-5 (identical idempotent writes per row-group). Drop REP once tuned.
    afm_fp8_kernel<<<batch * REP, 192, 0, stream>>>(
        conts, cates, emb, attn_W, attn_b, proj_W, fc_W, fc_b, out, batch - 1);
}